// Round 8
// baseline (519.871 us; speedup 1.0000x reference)
//
#include <hip/hip_runtime.h>
#include <hip/hip_bf16.h>
#include <math.h>

typedef __bf16 bf16_t;
typedef __bf16 bf16x4 __attribute__((ext_vector_type(4)));
typedef __bf16 bf16x8 __attribute__((ext_vector_type(8)));
typedef float  f32x4  __attribute__((ext_vector_type(4)));

#define B_   2
#define S_   2048
#define D_   4096
#define NH_  32
#define NKV_ 8
#define HD_  128
#define NREP_ 4
#define QKVN 6144   // fused QKV output width: 4096 q + 1024 k + 1024 v

static __device__ __forceinline__ void gload_lds16(const bf16_t* g, bf16_t* l) {
  __builtin_amdgcn_global_load_lds(
      (const __attribute__((address_space(1))) void*)g,
      (__attribute__((address_space(3))) void*)l, 16, 0, 0);
}

// ---------------- elementwise f32 -> bf16 convert (vectorized) ----------------
__global__ void convert_f32_bf16(const float* __restrict__ in, bf16_t* __restrict__ out,
                                 size_t n8) {
  size_t i = (size_t)blockIdx.x * blockDim.x + threadIdx.x;
  if (i >= n8) return;
  f32x4 a = *(const f32x4*)(in + i * 8);
  f32x4 b = *(const f32x4*)(in + i * 8 + 4);
  bf16x8 o;
  o[0] = (bf16_t)a[0]; o[1] = (bf16_t)a[1]; o[2] = (bf16_t)a[2]; o[3] = (bf16_t)a[3];
  o[4] = (bf16_t)b[0]; o[5] = (bf16_t)b[1]; o[6] = (bf16_t)b[2]; o[7] = (bf16_t)b[3];
  *(bf16x8*)(out + i * 8) = o;
}

// ---------------- transpose + convert: in (R,C) f32 -> out (C,R) bf16 ----------------
__global__ void transpose_convert(const float* __restrict__ in, bf16_t* __restrict__ out,
                                  int R, int C) {
  __shared__ float tile[32][33];
  const int c0 = blockIdx.x * 32, r0 = blockIdx.y * 32;
  const int tc = threadIdx.x & 31, tr = threadIdx.x >> 5;  // tr in 0..7
#pragma unroll
  for (int i = 0; i < 4; i++) {
    int r = tr + i * 8;
    tile[r][tc] = in[(size_t)(r0 + r) * C + c0 + tc];
  }
  __syncthreads();
#pragma unroll
  for (int i = 0; i < 4; i++) {
    int r = tr + i * 8;  // row of OUT tile = col of in
    out[(size_t)(c0 + r) * R + r0 + tc] = (bf16_t)tile[tc][r];
  }
}

// ---------------- transpose V: qkv cols [5120,6144) -> (B,NKV,HD,S) bf16 ----------------
__global__ void transpose_v(const bf16_t* __restrict__ qkv, bf16_t* __restrict__ out) {
  __shared__ bf16_t tile[32][33];
  const int t0 = blockIdx.x * 32, d0 = blockIdx.y * 32;
  const int bg = blockIdx.z, b = bg / NKV_, g = bg % NKV_;
  const bf16_t* ibase = qkv + (size_t)b * S_ * QKVN + 5120 + g * HD_;
  bf16_t* obase = out + ((size_t)b * NKV_ + g) * (size_t)HD_ * S_;
  const int tc = threadIdx.x & 31, tr = threadIdx.x >> 5;
#pragma unroll
  for (int i = 0; i < 4; i++) {
    int t = t0 + tr + i * 8;
    tile[tr + i * 8][tc] = ibase[(size_t)t * QKVN + d0 + tc];
  }
  __syncthreads();
#pragma unroll
  for (int i = 0; i < 4; i++) {
    int d = d0 + tr + i * 8;
    obase[(size_t)d * S_ + t0 + tc] = tile[tc][tr + i * 8];
  }
}

// ---------------- RoPE in-place on qkv buffer (row stride QKVN) ----------------
__global__ void rope_inplace(bf16_t* __restrict__ x, const float* __restrict__ cosT,
                             const float* __restrict__ sinT, int lgh, size_t nchunks) {
  size_t i = (size_t)blockIdx.x * blockDim.x + threadIdx.x;
  if (i >= nchunks) return;
  const int d8 = (int)(i & 15);
  const int h = (int)((i >> 4) & ((1u << lgh) - 1));
  const size_t pos = i >> (4 + lgh);
  const int s = (int)(pos & (S_ - 1));
  bf16_t* p = x + pos * QKVN + h * HD_ + d8 * 8;
  bf16x8 v = *(bf16x8*)p;
  f32x4 c  = *(const f32x4*)(cosT + (size_t)s * 64 + d8 * 4);
  f32x4 sn = *(const f32x4*)(sinT + (size_t)s * 64 + d8 * 4);
  bf16x8 o;
#pragma unroll
  for (int j = 0; j < 4; j++) {
    float re = (float)v[2 * j], im = (float)v[2 * j + 1];
    o[2 * j]     = (bf16_t)(re * c[j] - im * sn[j]);
    o[2 * j + 1] = (bf16_t)(re * sn[j] + im * c[j]);
  }
  *(bf16x8*)p = o;
}

// ---------------- 256x256 NT GEMM, BK=32, 4-buffer, 1 barrier/K-tile ----------------
// C(M,N) = A(M,K) @ Bt(N,K)^T. 512 threads = 8 waves (2M x 4N), wave tile 128x64.
// LDS: 4 K-tile buffers x (A[256][32] + B[256][32]) bf16 = 128 KiB dynamic.
// Paired-row macro layout: tile [256][32] stored as [128 macro-rows][8 slots of 16B];
// element (r,k) -> mr=r>>1, s0=4*(r&1)+(k>>3), slot s=s0^(mr&7). Stage = linear t*16B
// dest with inverse permutation folded into the global source (both-sides swizzle).
// Frag reads: 2 lanes/slot = 2-way = free. 32 MFMA/K-tile/wave, zero intra-phase RAW.
// Counted-vmcnt ledger: steady in-flight {t_{c+2}} -> stage t_{c+3} -> vmcnt(4).
template <typename OutT>
__global__ __launch_bounds__(512, 2) void gemm32(const bf16_t* __restrict__ Ag,
                                                 const bf16_t* __restrict__ Bg,
                                                 OutT* __restrict__ C,
                                                 int M, int N, int K) {
  extern __shared__ __align__(16) bf16_t lds[];  // 4 * 16384 elements
  const int t = threadIdx.x;
  const int w = t >> 6, l = t & 63;
  const int wm = w >> 2, wn = w & 3;
  const int lr = l & 15, lg = l >> 4;

  // XCD-chunked swizzle of flattened block id (grid % 8 == 0 for all our launches)
  const int nbx = gridDim.x;
  const int nwg = nbx * gridDim.y;
  const int bid = blockIdx.y * nbx + blockIdx.x;
  const int cpx = nwg >> 3;
  const int sid = (bid & 7) * cpx + (bid >> 3);
  const int n0 = (sid % nbx) * 256;
  const int m0 = (sid / nbx) * 256;

  // stage precompute: thread t writes 16B at linear dest t*16; source element:
  // s0 = (t&7)^((t>>3)&7); row = 2*(t>>3) + (s0>>2); col = (s0&3)*8
  const int s0t = (t & 7) ^ ((t >> 3) & 7);
  const int srow = 2 * (t >> 3) + (s0t >> 2);
  const int scol = (s0t & 3) * 8;

  auto stage = [&](int buf, int k0) {
    bf16_t* dst = lds + buf * 16384 + t * 8;
    gload_lds16(Ag + (size_t)(m0 + srow) * K + k0 + scol, dst);
    gload_lds16(Ag + (size_t)(m0 + 128 + srow) * K + k0 + scol, dst + 4096);
    gload_lds16(Bg + (size_t)(n0 + srow) * K + k0 + scol, dst + 8192);
    gload_lds16(Bg + (size_t)(n0 + 128 + srow) * K + k0 + scol, dst + 12288);
  };

  // frag-read offsets: slot is lane-constant: s = (4*(lr&1)+lg) ^ ((lr>>1)&7)
  const int sloff = (((4 * (lr & 1) + lg) ^ ((lr >> 1) & 7)) * 8);
  const int amr0 = wm * 64 + (lr >> 1);   // macro-row base for A frags (+ m*8)
  const int bmr0 = wn * 32 + (lr >> 1);   // macro-row base for B frags (+ n*8)

  auto readFrags = [&](bf16x8* fa, bf16x8* fb, int buf) {
    const bf16_t* base = lds + buf * 16384;
#pragma unroll
    for (int m = 0; m < 8; m++)
      fa[m] = *(const bf16x8*)(base + (amr0 + m * 8) * 64 + sloff);
#pragma unroll
    for (int n = 0; n < 4; n++)
      fb[n] = *(const bf16x8*)(base + 8192 + (bmr0 + n * 8) * 64 + sloff);
  };

  f32x4 acc[8][4];
  const f32x4 zero = {0.f, 0.f, 0.f, 0.f};
#pragma unroll
  for (int m = 0; m < 8; m++)
#pragma unroll
    for (int n = 0; n < 4; n++) acc[m][n] = zero;

  auto mfmaTile = [&](const bf16x8* fa, const bf16x8* fb) {
    __builtin_amdgcn_s_setprio(1);
#pragma unroll
    for (int m = 0; m < 8; m++)
#pragma unroll
      for (int n = 0; n < 4; n++)
        acc[m][n] = __builtin_amdgcn_mfma_f32_16x16x32_bf16(fa[m], fb[n], acc[m][n], 0, 0, 0);
    __builtin_amdgcn_s_setprio(0);
  };

  const int KT = K >> 5;  // K-tiles of 32 (here 128, even)

  bf16x8 fa0[8], fb0[4], fa1[8], fb1[4];

  // prologue: stage tiles 0,1,2; vmcnt(4) -> t0,t1 arrived, t2 in flight
  stage(0, 0);
  stage(1, 32);
  stage(2, 64);
  asm volatile("s_waitcnt vmcnt(4)" ::: "memory");
  __builtin_amdgcn_s_barrier();
  __builtin_amdgcn_sched_barrier(0);
  readFrags(fa0, fb0, 0);

  for (int c = 0; c < KT; c += 2) {
    // ---- phase c (cur = f0, next = f1) ----
    readFrags(fa1, fb1, (c + 1) & 3);                    // c+1 <= KT-1 always (KT even)
    if (c + 3 < KT) stage((c + 3) & 3, (c + 3) << 5);
    mfmaTile(fa0, fb0);
    if (c < KT - 3)       asm volatile("s_waitcnt vmcnt(4)" ::: "memory");
    else if (c == KT - 3) asm volatile("s_waitcnt vmcnt(0)" ::: "memory");
    __builtin_amdgcn_s_barrier();
    __builtin_amdgcn_sched_barrier(0);

    // ---- phase c+1 (cur = f1, next = f0) ----
    if (c + 2 < KT) readFrags(fa0, fb0, (c + 2) & 3);
    if (c + 4 < KT) stage((c + 4) & 3, (c + 4) << 5);
    mfmaTile(fa1, fb1);
    if (c + 1 < KT - 3)       asm volatile("s_waitcnt vmcnt(4)" ::: "memory");
    else if (c + 1 == KT - 3) asm volatile("s_waitcnt vmcnt(0)" ::: "memory");
    __builtin_amdgcn_s_barrier();
    __builtin_amdgcn_sched_barrier(0);
  }

  // ---- epilogue ----
#pragma unroll
  for (int m = 0; m < 8; m++)
#pragma unroll
    for (int n = 0; n < 4; n++) {
      const int row = m0 + wm * 128 + m * 16 + lg * 4;
      const int col = n0 + wn * 64 + n * 16 + lr;
#pragma unroll
      for (int r = 0; r < 4; r++) C[(size_t)(row + r) * N + col] = (OutT)acc[m][n][r];
    }
}

// ---------------- flash attention v4 (causal, GQA, balanced pairs, swapped QK^T) ----------------
// Q,K from fused qkv (Q-RoPE fused); Vt:(B,NKV,HD,S); O:(B,S,NH,HD) bf16.
#define QBLK 128
#define KVBLK 64
__global__ __launch_bounds__(256, 2) void flash_attn4(const bf16_t* __restrict__ QKV,
                                                      const bf16_t* __restrict__ Vt,
                                                      const float* __restrict__ cosT,
                                                      const float* __restrict__ sinT,
                                                      bf16_t* __restrict__ O) {
  const int pair = blockIdx.x;  // 0..7
  const int h = blockIdx.y, b = blockIdx.z;
  const int g = h >> 2;  // NREP=4
  const int t = threadIdx.x, w = t >> 6, l = t & 63;
  const int lr = l & 15, lg = l >> 4;

  __shared__ __align__(16) char lds[49152];
  char* Ks = lds;                     // [64][128] bf16, 256B rows, swizzled
  char* Vs = lds + 16384;             // [128][64] bf16, 128B rows, swizzled (V^T tile)
  char* Ps = lds + 32768 + w * 4096;  // per-wave [32][64] bf16, 128B rows, swizzled

  const float scale = 0.08838834764831845f;
  const int xm = (lr & 7) << 4;

  bf16x8 kpre[4], vpre[4];
  const int krow = t >> 4, ksl = t & 15;          // K: 64 rows x 16 slots
  const int vrow = t >> 3, vsl = t & 7;           // V^T: 128 rows x 8 slots
  auto loadKV = [&](int t0) {
#pragma unroll
    for (int i = 0; i < 4; i++)
      kpre[i] = *(const bf16x8*)&QKV[((size_t)b * S_ + t0 + krow + i * 16) * QKVN + 4096 +
                                     g * HD_ + ksl * 8];
#pragma unroll
    for (int i = 0; i < 4; i++)
      vpre[i] = *(const bf16x8*)&Vt[(((size_t)b * NKV_ + g) * HD_ + vrow + i * 32) * S_ +
                                    t0 + vsl * 8];
  };
  auto writeKV = [&]() {
#pragma unroll
    for (int i = 0; i < 4; i++) {
      const int row = krow + i * 16;
      *(bf16x8*)(Ks + row * 256 + ((ksl * 16) ^ ((row & 7) << 4))) = kpre[i];
    }
#pragma unroll
    for (int i = 0; i < 4; i++) {
      const int row = vrow + i * 32;
      *(bf16x8*)(Vs + row * 128 + ((vsl * 16) ^ ((row & 7) << 4))) = vpre[i];
    }
  };

  for (int phase = 0; phase < 2; phase++) {
    const int qtile = phase ? (15 - pair) : pair;
    const int q0 = qtile * QBLK;
    const int wq = q0 + w * 32;  // this wave's first q row

    // Q -> registers (B-operand layout), RoPE + scale fused
    bf16x8 qreg[2][4];
#pragma unroll
    for (int qt = 0; qt < 2; qt++) {
      const int s = wq + qt * 16 + lr;  // sequence position (< S_)
#pragma unroll
      for (int kk = 0; kk < 4; kk++) {
        bf16x8 v = *(const bf16x8*)&QKV[((size_t)b * S_ + s) * QKVN +
                                        h * HD_ + kk * 32 + lg * 8];
        f32x4 c4 = *(const f32x4*)(cosT + (size_t)s * 64 + kk * 16 + lg * 4);
        f32x4 s4 = *(const f32x4*)(sinT + (size_t)s * 64 + kk * 16 + lg * 4);
        bf16x8 o;
#pragma unroll
        for (int j = 0; j < 4; j++) {
          float re = (float)v[2 * j], im = (float)v[2 * j + 1];
          o[2 * j]     = (bf16_t)((re * c4[j] - im * s4[j]) * scale);
          o[2 * j + 1] = (bf16_t)((re * s4[j] + im * c4[j]) * scale);
        }
        qreg[qt][kk] = o;
      }
    }

    float mrun[2] = {-INFINITY, -INFINITY};
    float lrun[2] = {0.f, 0.f};
    f32x4 acc[2][8];
    const f32x4 zero = {0.f, 0.f, 0.f, 0.f};
#pragma unroll
    for (int qt = 0; qt < 2; qt++)
#pragma unroll
      for (int d = 0; d < 8; d++) acc[qt][d] = zero;

    const int nkb = (q0 + QBLK) >> 6;
    loadKV(0);  // prologue: tile 0 into regs
    for (int kb = 0; kb < nkb; kb++) {
      const int t0 = kb * KVBLK;
      __syncthreads();              // previous tile's LDS readers done
      writeKV();                    // regs -> LDS
      if (kb + 1 < nkb) loadKV(t0 + KVBLK);  // issue next tile's loads
      __syncthreads();

      if (t0 > wq + 31) continue;  // causal: wave has no work this tile

      // ---- S^T = K @ Q^T ----
      f32x4 st[4][2];
#pragma unroll
      for (int n = 0; n < 4; n++) { st[n][0] = zero; st[n][1] = zero; }
#pragma unroll
      for (int kk = 0; kk < 4; kk++) {
        const int colb = (kk * 64 + lg * 16) ^ xm;
#pragma unroll
        for (int n = 0; n < 4; n++) {
          const bf16x8 ak = *(const bf16x8*)(Ks + (n * 16 + lr) * 256 + colb);
          st[n][0] = __builtin_amdgcn_mfma_f32_16x16x32_bf16(ak, qreg[0][kk], st[n][0], 0, 0, 0);
          st[n][1] = __builtin_amdgcn_mfma_f32_16x16x32_bf16(ak, qreg[1][kk], st[n][1], 0, 0, 0);
        }
      }

      // ---- online softmax with defer-max ----
      const bool needmask = (t0 + KVBLK - 1 > wq);
#pragma unroll
      for (int qt = 0; qt < 2; qt++) {
        const int q = wq + qt * 16 + lr;
        if (needmask) {
#pragma unroll
          for (int n = 0; n < 4; n++)
#pragma unroll
            for (int r = 0; r < 4; r++)
              if (t0 + n * 16 + lg * 4 + r > q) st[n][qt][r] = -INFINITY;
        }
        float mx = -INFINITY;
#pragma unroll
        for (int n = 0; n < 4; n++)
#pragma unroll
          for (int r = 0; r < 4; r++) mx = fmaxf(mx, st[n][qt][r]);
        mx = fmaxf(mx, __shfl_xor(mx, 16));
        mx = fmaxf(mx, __shfl_xor(mx, 32));

        const bool nore = __all(mx <= mrun[qt] + 8.0f);
        float mnew, corr;
        if (nore) {
          mnew = mrun[qt];
        } else {
          mnew = fmaxf(mrun[qt], mx);
          corr = __expf(mrun[qt] - mnew);
        }
        float sum = 0.f;
        bf16x4 pk[4];
#pragma unroll
        for (int n = 0; n < 4; n++) {
#pragma unroll
          for (int r = 0; r < 4; r++) {
            const float p = __expf(st[n][qt][r] - mnew);
            sum += p;
            pk[n][r] = (bf16_t)p;
          }
        }
        sum += __shfl_xor(sum, 16);
        sum += __shfl_xor(sum, 32);
        if (nore) {
          lrun[qt] += sum;
        } else {
          lrun[qt] = lrun[qt] * corr + sum;
          mrun[qt] = mnew;
#pragma unroll
          for (int r = 0; r < 4; r++) {
            const float cb = __shfl(corr, lg * 4 + r);
#pragma unroll
            for (int db = 0; db < 8; db++) acc[qt][db][r] *= cb;
          }
        }
        {
          char* pbase = Ps + (qt * 16 + lr) * 128;
#pragma unroll
          for (int n = 0; n < 4; n++)
            *(bf16x4*)(pbase + ((n * 32 + lg * 8) ^ xm)) = pk[n];
        }
      }

      // ---- O += P @ V ----
#pragma unroll
      for (int kk = 0; kk < 2; kk++) {
        const int colb = (kk * 64 + lg * 16) ^ xm;
        const bf16x8 ap0 = *(const bf16x8*)(Ps + lr * 128 + colb);
        const bf16x8 ap1 = *(const bf16x8*)(Ps + (16 + lr) * 128 + colb);
#pragma unroll
        for (int db = 0; db < 8; db++) {
          const bf16x8 bv = *(const bf16x8*)(Vs + (db * 16 + lr) * 128 + colb);
          acc[0][db] = __builtin_amdgcn_mfma_f32_16x16x32_bf16(ap0, bv, acc[0][db], 0, 0, 0);
          acc[1][db] = __builtin_amdgcn_mfma_f32_16x16x32_bf16(ap1, bv, acc[1][db], 0, 0, 0);
        }
      }
    }

    // ---- epilogue: O = acc / l ----
#pragma unroll
    for (int qt = 0; qt < 2; qt++) {
      const float linv = 1.f / lrun[qt];
#pragma unroll
      for (int r = 0; r < 4; r++) {
        const float li = __shfl(linv, lg * 4 + r);
        const int q = wq + qt * 16 + lg * 4 + r;
#pragma unroll
        for (int db = 0; db < 8; db++)
          O[(((size_t)b * S_ + q) * NH_ + h) * HD_ + db * 16 + lr] = (bf16_t)(acc[qt][db][r] * li);
      }
    }
    __syncthreads();  // protect LDS before next phase restages
  }
}

extern "C" void kernel_launch(void* const* d_in, const int* in_sizes, int n_in,
                              void* d_out, int out_size, void* d_ws, size_t ws_size,
                              hipStream_t stream) {
  const float* x    = (const float*)d_in[0];
  const float* fcos = (const float*)d_in[1];
  const float* fsin = (const float*)d_in[2];
  const float* wq   = (const float*)d_in[3];
  const float* wk   = (const float*)d_in[4];
  const float* wv   = (const float*)d_in[5];
  const float* wo   = (const float*)d_in[6];
  float* out = (float*)d_out;

  char* ws = (char*)d_ws;
  bf16_t* x_bf   = (bf16_t*)(ws);               // 33.5 MB  (4096x4096 bf16)
  bf16_t* wqkvT  = (bf16_t*)(ws + 33554432);    // 50.3 MB  (6144x4096 bf16; later wo^T)
  bf16_t* qkv    = (bf16_t*)(ws + 83886080);    // 50.3 MB  (4096x6144 bf16)
  bf16_t* vt     = (bf16_t*)(ws + 134217728);   // 8.4 MB   (B,NKV,HD,S)
  bf16_t* attn   = (bf16_t*)(ws + 142606336);   // 33.5 MB  (4096x4096 bf16) end ~176 MB

  hipFuncSetAttribute(reinterpret_cast<const void*>(gemm32<bf16_t>),
                      hipFuncAttributeMaxDynamicSharedMemorySize, 131072);
  hipFuncSetAttribute(reinterpret_cast<const void*>(gemm32<float>),
                      hipFuncAttributeMaxDynamicSharedMemorySize, 131072);

  // 1. convert x to bf16
  convert_f32_bf16<<<8192, 256, 0, stream>>>(x, x_bf, (size_t)2097152);
  // 2. transpose+convert weights into fused (6144,4096) bf16 W^T
  transpose_convert<<<dim3(128, 128), 256, 0, stream>>>(wq, wqkvT, 4096, 4096);
  transpose_convert<<<dim3(32, 128), 256, 0, stream>>>(wk, wqkvT + (size_t)4096 * 4096, 4096, 1024);
  transpose_convert<<<dim3(32, 128), 256, 0, stream>>>(wv, wqkvT + (size_t)5120 * 4096, 4096, 1024);
  // 3. fused QKV projection: (4096,6144) bf16
  gemm32<bf16_t><<<dim3(24, 16), 512, 131072, stream>>>(x_bf, wqkvT, qkv, 4096, QKVN, 4096);
  // 4. RoPE in-place on k only (q-rope fused into flash)
  rope_inplace<<<2048, 256, 0, stream>>>(qkv + 4096, fcos, fsin, 3, (size_t)524288);
  // 5. V -> (B,NKV,HD,S)
  transpose_v<<<dim3(64, 4, 16), 256, 0, stream>>>(qkv, vt);
  // 6. wo^T into the wqkvT slab (QKV GEMM done reading it)
  transpose_convert<<<dim3(128, 128), 256, 0, stream>>>(wo, wqkvT, 4096, 4096);
  // 7. flash attention v4
  flash_attn4<<<dim3(8, 32, 2), 256, 0, stream>>>(qkv, vt, fcos, fsin, attn);
  // 8. output projection (f32 out)
  gemm32<float><<<dim3(16, 16), 512, 131072, stream>>>(attn, wqkvT, out, 4096, 4096, 4096);
}